// Round 9
// baseline (5932.943 us; speedup 1.0000x reference)
//
#include <hip/hip_runtime.h>

// NODE scan: 32 groups x 8 blocks; group = 16 batch rows; block j owns a
// 64-col slice of W1/W2, 64-ROW slice of W3 (partial-v reduce), 8 cols of Wr.
// R9 = R8 + (1) sc0 fast flags w/ sc1 backstop (probe-proven scope, no hang
// path: backstop check every 8 polls), (2) drain hygiene: out/lat buffered in
// LDS, flushed to HBM every 8 steps in the release->poll gap; x prefetch
// joins phase-B's drain. Data plane: sc0 iff probe proves, else sc0 sc1.

#define TT 1000
#define II 16
#define LL 128
#define HH 512
#define OO 64
#define BB 512

typedef _Float16 f16;
typedef _Float16 f16x8 __attribute__((ext_vector_type(8)));
typedef _Float16 f16x4 __attribute__((ext_vector_type(4)));
typedef float    f32x4 __attribute__((ext_vector_type(4)));
typedef unsigned u32x2 __attribute__((ext_vector_type(2)));
typedef unsigned u32x4 __attribute__((ext_vector_type(4)));

#define MFMA16(a, b, c) __builtin_amdgcn_mfma_f32_16x16x32_f16((a), (b), (c), 0, 0, 0)

// f16 row strides: row byte-size MUST be a multiple of 128 (XOR block size).
#define ZS2  256   // 512B: z 0..159 | vpT 64..191 | a2 192..255
#define W1S  192   // 384B = 3*128
#define W2S  512   // 1024B
#define W3S  64    // 128B
#define WRS  128   // 256B

// swizzled address: row-base + (2*colf16 ^ ((row&7)<<4))
#define SWB(rowptr, row, colf16) \
  ((void*)((char*)(rowptr) + ((2 * (colf16)) ^ (((row) & 7) << 4))))

struct Lds {
  f16 w1t[64][W1S];
  f16 w2t[64][W2S];
  f16 w3t[128][W3S];
  f16 wrt[16][WRS];
  f16 act[16][ZS2];
  float latb[8][16][20];   // 8-step latent slice buffer (stride 20: 2-way banks)
  float outb[8][16][12];   // 8-step out slice buffer
  float b1c[64], b2c[64], b3c[128], brc[16];
  int xtmp[8];
};

// ---- always-coherent (L3) primitives ----
__device__ __forceinline__ void st_sc1_u32(void* p, unsigned v) {
  asm volatile("global_store_dword %0, %1, off sc0 sc1" :: "v"(p), "v"(v) : "memory");
}
__device__ __forceinline__ unsigned ld_sc1_u32(const void* p) {
  unsigned r;
  asm volatile("global_load_dword %0, %1, off sc0 sc1\n\ts_waitcnt vmcnt(0)"
               : "=v"(r) : "v"(p) : "memory");
  return r;
}
// ---- XCD-L2 primitives (used only where probe proved coherence) ----
__device__ __forceinline__ void st_sc0_u32(void* p, unsigned v) {
  asm volatile("global_store_dword %0, %1, off sc0" :: "v"(p), "v"(v) : "memory");
}
__device__ __forceinline__ unsigned ld_sc0_u32(const void* p) {
  unsigned r;
  asm volatile("global_load_dword %0, %1, off sc0\n\ts_waitcnt vmcnt(0)"
               : "=v"(r) : "v"(p) : "memory");
  return r;
}
template <bool FAST> __device__ __forceinline__ void st_c_u2(void* p, u32x2 v) {
  if constexpr (FAST) asm volatile("global_store_dwordx2 %0, %1, off sc0"     :: "v"(p), "v"(v) : "memory");
  else                asm volatile("global_store_dwordx2 %0, %1, off sc0 sc1" :: "v"(p), "v"(v) : "memory");
}
template <bool FAST> __device__ __forceinline__ void st_c_u4(void* p, u32x4 v) {
  if constexpr (FAST) asm volatile("global_store_dwordx4 %0, %1, off sc0"     :: "v"(p), "v"(v) : "memory");
  else                asm volatile("global_store_dwordx4 %0, %1, off sc0 sc1" :: "v"(p), "v"(v) : "memory");
}
template <bool FAST> __device__ __forceinline__ u32x4 ld_c_u4(const void* p) {
  u32x4 r;
  if constexpr (FAST) asm volatile("global_load_dwordx4 %0, %1, off sc0"     : "=v"(r) : "v"(p) : "memory");
  else                asm volatile("global_load_dwordx4 %0, %1, off sc0 sc1" : "=v"(r) : "v"(p) : "memory");
  return r;
}
__device__ __forceinline__ void vm_drain() {
  asm volatile("s_waitcnt vmcnt(0)" ::: "memory");
  __builtin_amdgcn_sched_barrier(0);   // rule #18
}

// flag layout per group (stride 512 u32, 64B-spread):
// a1 fast j*16 | vp fast 128+j*16 | a1 slow 256+j*16 | vp slow 384+j*16
template <bool FAST>
__device__ void run_loop(Lds& sh, const float* __restrict__ x,
                         float* __restrict__ out, float* __restrict__ lat,
                         unsigned* __restrict__ fl,
                         f16* __restrict__ a1buf, f16* __restrict__ vpbuf,
                         int j, int g, int tid, int w, int lr, int lk) {
  const int r    = tid >> 4;
  const int cg   = tid & 15;
  const int lane = tid & 63;
  const size_t xoff = (size_t)(g * 16 + r) * TT * II + cg;
  float xr = 0.f;
  float hreg[8] = {0.f, 0.f, 0.f, 0.f, 0.f, 0.f, 0.f, 0.f};

  auto REL = [&](int fbase, int sbase, unsigned val) {
    vm_drain();
    __syncthreads();
    if (tid == 0) {
      if constexpr (FAST) st_sc0_u32(fl + fbase + j * 16, val);
      st_sc1_u32(fl + sbase + j * 16, val);
    }
  };
  auto WAIT = [&](int fbase, int sbase, unsigned tgt) {
    if (lane < 8) {   // per-wave poll (no barrier needed after)
      if constexpr (FAST) {
        const unsigned* f0 = fl + fbase + lane * 16;
        const unsigned* f1 = fl + sbase + lane * 16;
        unsigned c = 0;
        while (ld_sc0_u32(f0) < tgt) {
          if ((++c & 7u) == 0u && ld_sc1_u32(f1) >= tgt) break;  // liveness
        }
      } else {
        const unsigned* f1 = fl + sbase + lane * 16;
        while (ld_sc1_u32(f1) < tgt) { }
      }
    }
  };
  // flush 8 buffered steps [base, base+8) of lat+out slices to HBM
  auto FLUSH = [&](int base) {
    const int seg = tid >> 1, half = tid & 1;
    const int ss = seg >> 4, row = seg & 15;
    {
      float* dst = lat + ((size_t)(g * 16 + row) * TT + (base + ss)) * LL +
                   16 * j + half * 8;
      f32x4 v0 = *(const f32x4*)&sh.latb[ss][row][half * 8];
      f32x4 v1 = *(const f32x4*)&sh.latb[ss][row][half * 8 + 4];
      *(f32x4*)dst = v0;
      *(f32x4*)(dst + 4) = v1;
    }
    {
      float* dst = out + ((size_t)(g * 16 + row) * TT + (base + ss)) * OO +
                   8 * j + half * 4;
      *(f32x4*)dst = *(const f32x4*)&sh.outb[ss][row][half * 4];
    }
  };

  for (int t = 0; t < TT; ++t) {
    const int par = t & 1;
    f16* const a1b = a1buf + (size_t)(g * 2 + par) * (16 * 512);
    f16* const vpb = vpbuf + (size_t)(g * 2 + par) * (8 * 16 * 128);

    // -------- phase A: a1_chunk = relu(z @ W1_slice + b1) ------------------
    {
      const int n = w * 16 + lr;
      f32x4 c = {0.f, 0.f, 0.f, 0.f};
#pragma unroll
      for (int kt = 0; kt < 5; ++kt) {
        f16x8 wf = *(const f16x8*)SWB(&sh.w1t[n][0], n, kt * 32 + lk * 8);
        f16x8 zf = *(const f16x8*)SWB(&sh.act[lr][0], lr, kt * 32 + lk * 8);
        c = MFMA16(wf, zf, c);
      }
      f16x4 o;
#pragma unroll
      for (int e = 0; e < 4; ++e) {
        float vv = c[e] + sh.b1c[w * 16 + lk * 4 + e];
        vv = vv > 0.f ? vv : 0.f;
        o[e] = (f16)vv;
      }
      st_c_u2<FAST>(a1b + (size_t)lr * 512 + 64 * j + w * 16 + lk * 4,
                    __builtin_bit_cast(u32x2, o));
    }
    REL(0, 256, (unsigned)(t + 1));

    // -------- gap0: out_{t-1} -> LDS outb (no HBM store on serial path) ----
    if (t > 0 && w == 0) {
      f32x4 c = {0.f, 0.f, 0.f, 0.f};
#pragma unroll
      for (int kt = 0; kt < 4; ++kt) {
        f16x8 a = *(const f16x8*)SWB(&sh.act[lr][0], lr, kt * 32 + lk * 8);
        f16x8 b = *(const f16x8*)SWB(&sh.wrt[lr][0], lr, kt * 32 + lk * 8);
        c = MFMA16(a, b, c);
      }
      if (lr < 8) {
#pragma unroll
        for (int e = 0; e < 4; ++e)
          sh.outb[(t - 1) & 7][lk * 4 + e][lr] = c[e] + sh.brc[lr];
      }
    }

    // -------- WAIT a1 (per-wave), B reads fragments DIRECT from L2 ---------
    WAIT(0, 256, (unsigned)(t + 1));
    {
      const int bn = w * 16 + lr;
      xr = (t + 1 < TT) ? x[xoff + (size_t)(t + 1) * II] : 0.f;  // joins drain
      u32x4 araw[16];
#pragma unroll
      for (int kt = 0; kt < 16; ++kt)
        araw[kt] = ld_c_u4<FAST>(a1b + (size_t)lr * 512 + kt * 32 + lk * 8);
      vm_drain();
      f32x4 c0 = {0.f, 0.f, 0.f, 0.f}, c1 = {0.f, 0.f, 0.f, 0.f};
#pragma unroll
      for (int kt = 0; kt < 16; kt += 2) {
        f16x8 b0 = *(const f16x8*)SWB(&sh.w2t[bn][0], bn, kt * 32 + lk * 8);
        c0 = MFMA16(__builtin_bit_cast(f16x8, araw[kt]), b0, c0);
        f16x8 b1_ = *(const f16x8*)SWB(&sh.w2t[bn][0], bn, (kt + 1) * 32 + lk * 8);
        c1 = MFMA16(__builtin_bit_cast(f16x8, araw[kt + 1]), b1_, c1);
      }
#pragma unroll
      for (int e = 0; e < 4; ++e) {           // a2 chunk -> act cols 192..255
        float vv = c0[e] + c1[e] + sh.b2c[bn];
        vv = vv > 0.f ? vv : 0.f;
        *(f16*)SWB(&sh.act[lk * 4 + e][0], lk * 4 + e, 192 + bn) = (f16)vv;
      }
    }
    __syncthreads();   // a2 visible to all waves

    // -------- phase C: vp = a2 @ W3_rows; wave-local vpT + store -----------
    {
      const int nt0 = 2 * w, nt1 = 2 * w + 1;
      f32x4 c0 = {0.f, 0.f, 0.f, 0.f}, c1 = {0.f, 0.f, 0.f, 0.f};
#pragma unroll
      for (int kt = 0; kt < 2; ++kt) {
        f16x8 a = *(const f16x8*)SWB(&sh.act[lr][0], lr, 192 + kt * 32 + lk * 8);
        f16x8 b0 = *(const f16x8*)SWB(&sh.w3t[nt0 * 16 + lr][0], nt0 * 16 + lr, kt * 32 + lk * 8);
        c0 = MFMA16(a, b0, c0);
        f16x8 b1_ = *(const f16x8*)SWB(&sh.w3t[nt1 * 16 + lr][0], nt1 * 16 + lr, kt * 32 + lk * 8);
        c1 = MFMA16(a, b1_, c1);
      }
#pragma unroll
      for (int e = 0; e < 4; ++e) {           // vpT cols 64+32w..64+32w+31
        *(f16*)SWB(&sh.act[lk * 4 + e][0], lk * 4 + e, 64 + nt0 * 16 + lr) = (f16)c0[e];
        *(f16*)SWB(&sh.act[lk * 4 + e][0], lk * 4 + e, 64 + nt1 * 16 + lr) = (f16)c1[e];
      }
      // wave stores ONLY the cols it wrote (no barrier needed)
      const int vr = lane >> 2, vc = (lane & 3) * 8;
      u32x4 vv = *(const u32x4*)SWB(&sh.act[vr][0], vr, 64 + 32 * w + vc);
      st_c_u4<FAST>(vpb + (size_t)j * 2048 + (size_t)vr * 128 + 32 * w + vc, vv);
    }
    REL(128, 384, (unsigned)(t + 1));

    // -------- gap1: HBM flush of 8 buffered steps (1/8 of steps) -----------
    if ((t & 7) == 0 && t > 0) FLUSH(t - 8);

    // -------- WAIT vp (per-wave) -------------------------------------------
    WAIT(128, 384, (unsigned)(t + 1));

    // -------- phase D: v = sum_j vp_j + b3; h += 0.1v; rebuild z; latb -----
    {
      const f16* vb = vpb + (size_t)r * 128 + cg * 8;
      u32x4 p[8];
#pragma unroll
      for (int m = 0; m < 8; ++m) p[m] = ld_c_u4<FAST>(vb + (size_t)m * 2048);
      vm_drain();
      float sum[8] = {0.f, 0.f, 0.f, 0.f, 0.f, 0.f, 0.f, 0.f};
#pragma unroll
      for (int m = 0; m < 8; ++m) {
        f16x8 ph = __builtin_bit_cast(f16x8, p[m]);
#pragma unroll
        for (int e = 0; e < 8; ++e) sum[e] += (float)ph[e];
      }
      f16x8 zf;
#pragma unroll
      for (int e = 0; e < 8; ++e) {
        hreg[e] += 0.1f * (sum[e] + sh.b3c[cg * 8 + e]);
        zf[e] = (f16)hreg[e];
      }
      *(f16x8*)SWB(&sh.act[r][0], r, cg * 8) = zf;
      *(f16*)SWB(&sh.act[r][0], r, 128 + cg) = (f16)xr;
      *(f16*)SWB(&sh.act[r][0], r, 144 + cg) = (f16)0.f;   // re-zero K pad
      if ((cg >> 1) == j) {   // buffer this block's 16-col latent slice
        f32x4 h0 = {hreg[0], hreg[1], hreg[2], hreg[3]};
        f32x4 h1 = {hreg[4], hreg[5], hreg[6], hreg[7]};
        *(f32x4*)&sh.latb[t & 7][r][(cg & 1) * 8] = h0;
        *(f32x4*)&sh.latb[t & 7][r][(cg & 1) * 8 + 4] = h1;
      }
    }
    __syncthreads();   // z ready for next A
  }

  // -------- epilogue: out_{TT-1} -> outb slot 7, then final flush ----------
  if (w == 0) {
    f32x4 c = {0.f, 0.f, 0.f, 0.f};
#pragma unroll
    for (int kt = 0; kt < 4; ++kt) {
      f16x8 a = *(const f16x8*)SWB(&sh.act[lr][0], lr, kt * 32 + lk * 8);
      f16x8 b = *(const f16x8*)SWB(&sh.wrt[lr][0], lr, kt * 32 + lk * 8);
      c = MFMA16(a, b, c);
    }
    if (lr < 8) {
#pragma unroll
      for (int e = 0; e < 4; ++e)
        sh.outb[7][lk * 4 + e][lr] = c[e] + sh.brc[lr];
    }
  }
  __syncthreads();
  FLUSH(TT - 8);
}

__launch_bounds__(256, 1)
__global__ void node_scan_kernel(
    const float* __restrict__ x,
    const float* __restrict__ W1, const float* __restrict__ b1,
    const float* __restrict__ W2, const float* __restrict__ b2,
    const float* __restrict__ W3, const float* __restrict__ b3,
    const float* __restrict__ Wr, const float* __restrict__ br,
    float* __restrict__ out,
    unsigned* __restrict__ flags, unsigned* __restrict__ xccbuf,
    unsigned* __restrict__ pflag, unsigned* __restrict__ pack,
    unsigned* __restrict__ verd,  unsigned* __restrict__ pdata,
    f16* __restrict__ a1buf, f16* __restrict__ vpbuf)
{
  __shared__ Lds s;
  const int tid  = threadIdx.x;
  const int bid  = blockIdx.x;
  const int q    = bid >> 3;
  const int j    = q & 7;
  const int g    = (bid & 7) + 8 * (q >> 3);    // group 0..31 (co-XCD heuristic)
  const int lane = tid & 63;
  const int w    = tid >> 6;
  const int lr   = lane & 15;
  const int lk   = lane >> 4;

  float* lat = out + (size_t)BB * TT * OO;

  // ---------------- prologue: weights -> LDS (transposed, f16, swizzled) ---
  { int n = tid & 63, ks = tid >> 6;
    for (int k = ks; k < 144; k += 4)
      *(f16*)SWB(&s.w1t[n][0], n, k) = (f16)W1[(size_t)k * HH + 64 * j + n];
    for (int k = 144 + ks; k < 160; k += 4)
      *(f16*)SWB(&s.w1t[n][0], n, k) = (f16)0.f;
    for (int k = ks; k < HH; k += 4)
      *(f16*)SWB(&s.w2t[n][0], n, k) = (f16)W2[(size_t)k * HH + 64 * j + n];
  }
  for (int idx = tid; idx < 128 * 64; idx += 256) {
    int kl = idx >> 7, n = idx & 127;
    *(f16*)SWB(&s.w3t[n][0], n, kl) = (f16)W3[(size_t)(64 * j + kl) * LL + n];
  }
  { int n = tid & 15, ks = tid >> 4;
    for (int k = ks; k < LL; k += 16)
      *(f16*)SWB(&s.wrt[n][0], n, k) =
          (n < 8) ? (f16)Wr[(size_t)k * OO + 8 * j + n] : (f16)0.f;
  }
  if (tid < 64)       { s.b1c[tid] = b1[64 * j + tid]; s.b2c[tid] = b2[64 * j + tid]; }
  else if (tid < 192) { s.b3c[tid - 64] = b3[tid - 64]; }
  else if (tid < 208) { int n = tid - 192; s.brc[n] = (n < 8) ? br[8 * j + n] : 0.f; }
  for (int i = tid; i < 16 * ZS2; i += 256) ((f16*)s.act)[i] = (f16)0.f;

  // ---------------- XCD-placement exchange (sc1, proven live) --------------
  int xcc;
  asm volatile("s_getreg_b32 %0, hwreg(HW_REG_XCC_ID)" : "=s"(xcc));
  xcc &= 15;
  if (tid == 0) { st_sc1_u32(xccbuf + g * 8 + j, 0x100u | (unsigned)xcc); vm_drain(); }
  if (tid < 8) {
    unsigned v;
    const unsigned* p = xccbuf + g * 8 + tid;
    do { v = ld_sc1_u32(p); } while (!(v & 0x100u));
    s.xtmp[tid] = (int)(v & 0xffu);
  }
  __syncthreads();
  bool fast = true;
  for (int k2 = 1; k2 < 8; ++k2) fast = fast && (s.xtmp[k2] == s.xtmp[0]);

  // ---------------- sc0 coherence probe (3 rounds, no sc0 spin) ------------
  unsigned okbit = 1u;
  if (fast) {
    unsigned* pd = pdata + g * 8;
    unsigned* pf = pflag + g * 8;
    unsigned* pa = pack  + g * 8;
    const unsigned X = 0x51A00000u | ((unsigned)j << 4);
#pragma unroll 1
    for (int rnd = 0; rnd < 3; ++rnd) {
      unsigned val = (rnd == 1) ? (X | 1u) : X;   // rnd2 restores X
      if (tid == 0) {
        st_sc0_u32(pd + j, val);
        vm_drain();
        st_sc1_u32(pf + j, (unsigned)(rnd + 1));
        vm_drain();
      }
      if (tid < 8) {
        while (ld_sc1_u32(pf + tid) < (unsigned)(rnd + 1)) { }
        if (rnd < 2) {
          unsigned exp = 0x51A00000u | ((unsigned)tid << 4) | (rnd == 1 ? 1u : 0u);
          if (ld_sc0_u32(pd + tid) != exp) okbit = 0u;
        }
      }
      __syncthreads();
      if (tid == 0) { st_sc1_u32(pa + j, (unsigned)(rnd + 1)); vm_drain(); }
      if (tid < 8) { while (ld_sc1_u32(pa + tid) < (unsigned)(rnd + 1)) { } }
      __syncthreads();
    }
    if (tid < 8) s.xtmp[tid] = (int)okbit;
    __syncthreads();
    for (int k2 = 0; k2 < 8; ++k2) fast = fast && (s.xtmp[k2] != 0);
  }
  // ---------------- verdict exchange: group-uniform FAST/SLOW --------------
  if (tid == 0) { st_sc1_u32(verd + g * 8 + j, 0x100u | (fast ? 1u : 0u)); vm_drain(); }
  if (tid < 8) {
    unsigned v;
    const unsigned* p = verd + g * 8 + tid;
    do { v = ld_sc1_u32(p); } while (!(v & 0x100u));
    s.xtmp[tid] = (int)(v & 1u);
  }
  __syncthreads();
  bool FASTRUN = true;
  for (int k2 = 0; k2 < 8; ++k2) FASTRUN = FASTRUN && (s.xtmp[k2] != 0);

  // z_0 = [0 | x_0 | 0]
  { const int rr = tid >> 4, cc = tid & 15;
    *(f16*)SWB(&s.act[rr][0], rr, 128 + cc) =
        (f16)x[(size_t)(g * 16 + rr) * TT * II + cc]; }
  __syncthreads();

  unsigned* const fl = flags + g * 512;
  if (FASTRUN) run_loop<true >(s, x, out, lat, fl, a1buf, vpbuf, j, g, tid, w, lr, lk);
  else         run_loop<false>(s, x, out, lat, fl, a1buf, vpbuf, j, g, tid, w, lr, lk);
}

extern "C" void kernel_launch(void* const* d_in, const int* in_sizes, int n_in,
                              void* d_out, int out_size, void* d_ws, size_t ws_size,
                              hipStream_t stream) {
  const float* x  = (const float*)d_in[0];
  const float* W1 = (const float*)d_in[1];
  const float* b1 = (const float*)d_in[2];
  const float* W2 = (const float*)d_in[3];
  const float* b2 = (const float*)d_in[4];
  const float* W3 = (const float*)d_in[5];
  const float* b3 = (const float*)d_in[6];
  const float* Wr = (const float*)d_in[7];
  const float* br = (const float*)d_in[8];
  float* out = (float*)d_out;

  // ws: [0,64K) flags (32 groups x 512 u32: fast/slow a1+vp, 64B-spread) |
  // [64K) xcc | [65K) pflag | [66K) pack | [67K) verd (memset 0..68K) |
  // [68K,69K) pdata (sc0 probe, NOT memset; rnd2 restores) |
  // [128K) 1MB a1buf | [128K+1M) 2MB vpbuf
  unsigned* flags  = (unsigned*)d_ws;
  unsigned* xccbuf = (unsigned*)((char*)d_ws + 65536);
  unsigned* pflag  = (unsigned*)((char*)d_ws + 66560);
  unsigned* pack   = (unsigned*)((char*)d_ws + 67584);
  unsigned* verd   = (unsigned*)((char*)d_ws + 68608);
  unsigned* pdata  = (unsigned*)((char*)d_ws + 69632);
  f16* a1buf = (f16*)((char*)d_ws + 131072);
  f16* vpbuf = (f16*)((char*)d_ws + 131072 + (1 << 20));

  hipMemsetAsync(d_ws, 0, 69632, stream);  // flags + probe ctrl (not pdata)
  node_scan_kernel<<<256, 256, 0, stream>>>(x, W1, b1, W2, b2, W3, b3, Wr, br,
                                            out, flags, xccbuf, pflag, pack,
                                            verd, pdata, a1buf, vpbuf);
}